// Round 1
// baseline (942.387 us; speedup 1.0000x reference)
//
#include <hip/hip_runtime.h>

namespace {
constexpr int B_G = 131072;     // graphs
constexpr int P   = 22;         // players per graph (pad/trunc)
constexpr int F   = 14;         // features
constexpr int NF  = P * F;      // 308
constexpr int H1  = 256;
constexpr int H2  = 128;
constexpr int N_NODES = B_G * P;   // 2883584

constexpr int G    = 16;        // graphs per block
constexpr int KC1  = 28;        // 308 = 11 * 28
constexpr int NCH1 = 11;
constexpr int KC2  = 32;        // 256 = 8 * 32
constexpr int NCH2 = 8;
constexpr int NFP  = 309;       // padded strides (bank conflicts / alignment)
constexpr int H1P  = 260;       // 260*4 % 16 == 0 -> float4 rows stay aligned
constexpr int H2P  = 132;       // 132*4 % 16 == 0
}

__global__ __launch_bounds__(256, 2)
void fused_mlp_kernel(const float* __restrict__ x,
                      const int* __restrict__ batch,
                      const float* __restrict__ W1, const float* __restrict__ b1,
                      const float* __restrict__ W2, const float* __restrict__ b2,
                      const float* __restrict__ W3, const float* __restrict__ b3,
                      float* __restrict__ out)
{
    __shared__ float s_flat[G][NFP];   // 19776 B
    __shared__ float s_h1[G][H1P];     // 16640 B
    __shared__ float s_h2[G][H2P];     //  8448 B
    __shared__ float s_w[KC1 * H1];    // 28672 B (reused: W1 chunk / W2 chunk / all of W3)
    __shared__ int   s_start[G + 1];

    const int t    = threadIdx.x;
    const int gblk = blockIdx.x * G;

    // ---- 1. graph starts: windowed binary search (guess = 22*g), verified w/ fallback ----
    if (t <= G) {
        const int target = gblk + t;
        const long long guess = (long long)target * P;
        long long wl = guess - 5001; if (wl < 0) wl = 0;
        long long wh = guess + 5001; if (wh > N_NODES) wh = N_NODES;
        int lo = (int)wl, hi = (int)wh;
        while (lo < hi) { int mid = (lo + hi) >> 1; if (batch[mid] < target) lo = mid + 1; else hi = mid; }
        const bool ok = (lo == 0 || batch[lo - 1] < target) &&
                        (lo == N_NODES || batch[lo] >= target);
        if (!ok) {   // essentially never taken; guarantees correctness
            lo = 0; hi = N_NODES;
            while (lo < hi) { int mid = (lo + hi) >> 1; if (batch[mid] < target) lo = mid + 1; else hi = mid; }
        }
        s_start[t] = lo;
    }
    __syncthreads();

    // ---- 2. gather + zero-pad into LDS flat[g][308] ----
    for (int idx = t; idx < G * NF; idx += 256) {
        const int g = idx / NF;
        const int r = idx - g * NF;          // 0..307
        const int p = r / F;
        const int s = s_start[g];
        const int cnt = s_start[g + 1] - s;  // may exceed P -> truncation via p<=21
        float v = 0.0f;
        if (p < cnt) {
            const int f = r - p * F;
            v = x[(s + p) * F + f];
        }
        s_flat[g][r] = v;
    }
    // (first barrier of the GEMM1 chunk loop orders this before any compute)

    // ---- 3. GEMM1: h1[16][256] = relu(flat @ W1^T + b1), K=308 in 11 chunks of 28 ----
    const int j1 = (t & 31) * 8;        // 8 contiguous outputs
    const int ga = (t >> 5) * 2;        // 2 graphs
    float acc[2][8];
    #pragma unroll
    for (int i = 0; i < 2; ++i)
        #pragma unroll
        for (int m = 0; m < 8; ++m) acc[i][m] = 0.0f;

    for (int c = 0; c < NCH1; ++c) {
        const int k0 = c * KC1;
        __syncthreads();                // WAR on s_w (and orders gather on c==0)
        {   // stage W1[t][k0..k0+27] -> s_w[kk][j=t]   (aligned float4 reads; 2-way LDS writes = free)
            const float* src = W1 + t * NF + k0;
            float4 v[7];
            #pragma unroll
            for (int q = 0; q < 7; ++q) v[q] = reinterpret_cast<const float4*>(src)[q];
            #pragma unroll
            for (int q = 0; q < 7; ++q) {
                s_w[(q * 4 + 0) * H1 + t] = v[q].x;
                s_w[(q * 4 + 1) * H1 + t] = v[q].y;
                s_w[(q * 4 + 2) * H1 + t] = v[q].z;
                s_w[(q * 4 + 3) * H1 + t] = v[q].w;
            }
        }
        __syncthreads();
        #pragma unroll 4
        for (int kk = 0; kk < KC1; ++kk) {
            const float* wrow = &s_w[kk * H1];
            const float4 wa = *reinterpret_cast<const float4*>(wrow + j1);
            const float4 wb = *reinterpret_cast<const float4*>(wrow + j1 + 4);
            const float f0 = s_flat[ga][k0 + kk];       // wave-broadcast
            const float f1 = s_flat[ga + 1][k0 + kk];
            const float w[8] = {wa.x, wa.y, wa.z, wa.w, wb.x, wb.y, wb.z, wb.w};
            #pragma unroll
            for (int m = 0; m < 8; ++m) {
                acc[0][m] = fmaf(f0, w[m], acc[0][m]);
                acc[1][m] = fmaf(f1, w[m], acc[1][m]);
            }
        }
    }
    {   // bias + relu -> s_h1
        const float4 ba4 = *reinterpret_cast<const float4*>(b1 + j1);
        const float4 bb4 = *reinterpret_cast<const float4*>(b1 + j1 + 4);
        const float bias[8] = {ba4.x, ba4.y, ba4.z, ba4.w, bb4.x, bb4.y, bb4.z, bb4.w};
        #pragma unroll
        for (int i = 0; i < 2; ++i) {
            float o[8];
            #pragma unroll
            for (int m = 0; m < 8; ++m) o[m] = fmaxf(acc[i][m] + bias[m], 0.0f);
            *reinterpret_cast<float4*>(&s_h1[ga + i][j1])     = make_float4(o[0], o[1], o[2], o[3]);
            *reinterpret_cast<float4*>(&s_h1[ga + i][j1 + 4]) = make_float4(o[4], o[5], o[6], o[7]);
        }
    }

    // ---- 4. GEMM2: h2[16][128] = relu(h1 @ W2^T + b2), K=256 in 8 chunks of 32 ----
    const int j2 = (t & 31) * 4;
    const int gb = (t >> 5) * 2;
    float acc2[2][4];
    #pragma unroll
    for (int i = 0; i < 2; ++i)
        #pragma unroll
        for (int m = 0; m < 4; ++m) acc2[i][m] = 0.0f;

    for (int c = 0; c < NCH2; ++c) {
        const int k0 = c * KC2;
        __syncthreads();                // WAR on s_w; also orders s_h1 writes on c==0
        {   // stage W2[row][k0+half*16 .. +15] -> s_w[kk][row]
            const int row  = t & 127;
            const int half = t >> 7;
            const float* src = W2 + row * H1 + k0 + half * 16;
            float4 v[4];
            #pragma unroll
            for (int q = 0; q < 4; ++q) v[q] = reinterpret_cast<const float4*>(src)[q];
            #pragma unroll
            for (int q = 0; q < 4; ++q) {
                const int kk = half * 16 + q * 4;
                s_w[(kk + 0) * H2 + row] = v[q].x;
                s_w[(kk + 1) * H2 + row] = v[q].y;
                s_w[(kk + 2) * H2 + row] = v[q].z;
                s_w[(kk + 3) * H2 + row] = v[q].w;
            }
        }
        __syncthreads();
        #pragma unroll 4
        for (int kk = 0; kk < KC2; ++kk) {
            const float4 w4 = *reinterpret_cast<const float4*>(&s_w[kk * H2 + j2]);
            const float f0 = s_h1[gb][k0 + kk];
            const float f1 = s_h1[gb + 1][k0 + kk];
            acc2[0][0] = fmaf(f0, w4.x, acc2[0][0]);
            acc2[0][1] = fmaf(f0, w4.y, acc2[0][1]);
            acc2[0][2] = fmaf(f0, w4.z, acc2[0][2]);
            acc2[0][3] = fmaf(f0, w4.w, acc2[0][3]);
            acc2[1][0] = fmaf(f1, w4.x, acc2[1][0]);
            acc2[1][1] = fmaf(f1, w4.y, acc2[1][1]);
            acc2[1][2] = fmaf(f1, w4.z, acc2[1][2]);
            acc2[1][3] = fmaf(f1, w4.w, acc2[1][3]);
        }
    }
    {   // bias + relu -> s_h2
        const float4 b24 = *reinterpret_cast<const float4*>(b2 + j2);
        const float bias2[4] = {b24.x, b24.y, b24.z, b24.w};
        #pragma unroll
        for (int i = 0; i < 2; ++i) {
            float o[4];
            #pragma unroll
            for (int m = 0; m < 4; ++m) o[m] = fmaxf(acc2[i][m] + bias2[m], 0.0f);
            *reinterpret_cast<float4*>(&s_h2[gb + i][j2]) = make_float4(o[0], o[1], o[2], o[3]);
        }
    }

    // ---- 5. GEMM3: logits[16][22] = h2 @ W3^T + b3 ----
    __syncthreads();                     // WAR on s_w vs GEMM2 compute
    for (int idx = t; idx < (P * H2) / 4; idx += 256)   // stage all of W3 (row-major copy)
        reinterpret_cast<float4*>(s_w)[idx] = reinterpret_cast<const float4*>(W3)[idx];
    __syncthreads();

    for (int idx = t; idx < G * P; idx += 256) {        // 352 items, <=2 per thread
        const int g = idx / P;
        const int j = idx - g * P;
        float a = b3[j];
        #pragma unroll
        for (int k4 = 0; k4 < H2 / 4; ++k4) {
            const float4 h  = *reinterpret_cast<const float4*>(&s_h2[g][k4 * 4]);
            const float4 w4 = reinterpret_cast<const float4*>(s_w)[j * (H2 / 4) + k4];
            a = fmaf(h.x, w4.x, a);
            a = fmaf(h.y, w4.y, a);
            a = fmaf(h.z, w4.z, a);
            a = fmaf(h.w, w4.w, a);
        }
        out[(gblk + g) * P + j] = a;
    }
}

extern "C" void kernel_launch(void* const* d_in, const int* in_sizes, int n_in,
                              void* d_out, int out_size, void* d_ws, size_t ws_size,
                              hipStream_t stream) {
    const float* x     = (const float*)d_in[0];
    const int*   batch = (const int*)  d_in[1];
    const float* W1    = (const float*)d_in[2];
    const float* b1    = (const float*)d_in[3];
    const float* W2    = (const float*)d_in[4];
    const float* b2    = (const float*)d_in[5];
    const float* W3    = (const float*)d_in[6];
    const float* b3    = (const float*)d_in[7];
    float* out = (float*)d_out;

    fused_mlp_kernel<<<dim3(B_G / G), dim3(256), 0, stream>>>(
        x, batch, W1, b1, W2, b2, W3, b3, out);
}

// Round 2
// 141.275 us; speedup vs baseline: 6.6706x; 6.6706x over previous
//
#include <hip/hip_runtime.h>
#include <hip/hip_bf16.h>

typedef __attribute__((ext_vector_type(8))) short bf16x8;
typedef __attribute__((ext_vector_type(4))) float f32x4;

namespace {
constexpr int B_G = 131072;     // graphs
constexpr int P   = 22;
constexpr int F   = 14;
constexpr int NF  = 308;        // P*F
constexpr int H1  = 256;
constexpr int H2  = 128;
constexpr long long N_NODES = (long long)B_G * P;

constexpr int G    = 32;        // graphs per block
constexpr int NBLK = B_G / G;   // 4096

constexpr int KS1 = 10;         // ceil(308/32)
constexpr int KS2 = 8;          // 256/32
constexpr int KS3 = 4;          // 128/32
constexpr int JT1 = 16;         // 256/16 output tiles
constexpr int JT2 = 8;          // 128/16
constexpr int JT3 = 2;          // 32/16 (22 padded to 32)

// d_ws byte offsets for packed weight fragments (each fragment = 64 lanes * 16B = 1KB)
constexpr int W1HI = 0;
constexpr int W1LO = W1HI + KS1 * JT1 * 1024;   // 163840
constexpr int W2HI = W1LO + KS1 * JT1 * 1024;   // 327680
constexpr int W2LO = W2HI + KS2 * JT2 * 1024;   // 393216
constexpr int W3HI = W2LO + KS2 * JT2 * 1024;   // 458752
constexpr int W3LO = W3HI + KS3 * JT3 * 1024;   // 466944
constexpr int CVT_PAIRS = (KS1*JT1 + KS2*JT2 + KS3*JT3) * 256;  // 59392 dwords
}

__device__ __forceinline__ unsigned short f2bf(float v) {
    __hip_bfloat16 h = __float2bfloat16(v);
    return *reinterpret_cast<unsigned short*>(&h);
}
__device__ __forceinline__ float bf2f(unsigned short u) {
    __hip_bfloat16 h;
    *reinterpret_cast<unsigned short*>(&h) = u;
    return __bfloat162float(h);
}

// ---- one-time (per launch) weight conversion: fp32 -> bf16 hi/lo, MFMA-fragment order ----
__global__ void convert_w_kernel(const float* __restrict__ W1,
                                 const float* __restrict__ W2,
                                 const float* __restrict__ W3,
                                 unsigned* __restrict__ ws)
{
    int p = blockIdx.x * 256 + threadIdx.x;       // dword index (2 bf16 elems)
    if (p >= CVT_PAIRS) return;
    const int n1 = KS1 * JT1 * 256;               // 40960
    const int n2 = KS2 * JT2 * 256;               // 16384
    const float* W; int NK, NJ, stride, JT, hiB, loB, pl;
    if (p < n1)            { W = W1; NK = NF;  NJ = 256; stride = NF;  JT = JT1; hiB = W1HI/4; loB = W1LO/4; pl = p; }
    else if (p < n1 + n2)  { W = W2; NK = 256; NJ = 128; stride = 256; JT = JT2; hiB = W2HI/4; loB = W2LO/4; pl = p - n1; }
    else                   { W = W3; NK = 128; NJ = 22;  stride = 128; JT = JT3; hiB = W3HI/4; loB = W3LO/4; pl = p - n1 - n2; }

    const int e2   = pl & 3;                      // dword within lane's 8 elems
    const int lane = (pl >> 2) & 63;
    const int jt   = (pl >> 8) % JT;
    const int ks   = (pl >> 8) / JT;
    const int j    = jt * 16 + (lane & 15);
    const int kb   = ks * 32 + (lane >> 4) * 8 + e2 * 2;

    unsigned hi = 0, lo = 0;
    #pragma unroll
    for (int q = 0; q < 2; ++q) {
        const int k = kb + q;
        const float v = (k < NK && j < NJ) ? W[j * stride + k] : 0.0f;
        const unsigned short h = f2bf(v);
        const unsigned short l = f2bf(v - bf2f(h));
        hi |= (unsigned)h << (16 * q);
        lo |= (unsigned)l << (16 * q);
    }
    ws[hiB + pl] = hi;
    ws[loB + pl] = lo;
}

// ---- main fused kernel: gather -> GEMM1 -> GEMM2 -> GEMM3, all MFMA bf16 3-term split ----
__global__ __launch_bounds__(256, 2)
void mlp_mfma_kernel(const float* __restrict__ x,
                     const int* __restrict__ batch,
                     const float* __restrict__ b1,
                     const float* __restrict__ b2,
                     const float* __restrict__ b3,
                     const unsigned short* __restrict__ ws,
                     float* __restrict__ out)
{
    // Activation scratch, tiled layout [ks][kb4][graph G][e8] bf16 (conflict-free b128 reads).
    // A1(hi 0..10240, lo 10240..20480 ush) ; after barrier reused:
    // A2(hi 0..8192, lo 8192..16384) ; A3(hi 16384..20480, lo 20480..24576)
    __shared__ __align__(16) unsigned short s_scr[24576];   // 49152 B
    __shared__ float s_b1[256], s_b2[128], s_b3[32];
    __shared__ int s_start[G + 1];

    const int t    = threadIdx.x;
    const int g0   = blockIdx.x * G;
    const int lane = t & 63;
    const int wv   = t >> 6;          // wave 0..3
    const int r16  = lane & 15;
    const int kq   = lane >> 4;       // 0..3

    if (t < 256) s_b1[t] = b1[t];
    if (t < 128) s_b2[t] = b2[t];
    if (t < 32)  s_b3[t] = (t < 22) ? b3[t] : 0.0f;

    // graph starts: windowed binary search with verified fallback
    if (t <= G) {
        const int target = g0 + t;
        long long wl = (long long)target * P - 5001; if (wl < 0) wl = 0;
        long long wh = (long long)target * P + 5001; if (wh > N_NODES) wh = N_NODES;
        int lo = (int)wl, hi = (int)wh;
        while (lo < hi) { int mid = (lo + hi) >> 1; if (batch[mid] < target) lo = mid + 1; else hi = mid; }
        const bool ok = (lo == 0 || batch[lo - 1] < target) &&
                        (lo == (int)N_NODES || batch[lo] >= target);
        if (!ok) {
            lo = 0; hi = (int)N_NODES;
            while (lo < hi) { int mid = (lo + hi) >> 1; if (batch[mid] < target) lo = mid + 1; else hi = mid; }
        }
        s_start[t] = lo;
    }

    // pre-zero A1 (hi+lo = 40960 B = 2560 * 16B)
    for (int i = t; i < 2560; i += 256)
        reinterpret_cast<uint4*>(s_scr)[i] = make_uint4(0u, 0u, 0u, 0u);
    __syncthreads();

    // ---- gather + fp32->bf16 hi/lo split into tiled LDS ----
    const int s0 = s_start[0], s1 = s_start[G];
    for (int i = s0 + t; i < s1; i += 256) {
        const int gl = batch[i] - g0;
        const int pp = i - s_start[gl];
        if (pp < P) {
            const float2* xr = reinterpret_cast<const float2*>(x + (size_t)i * F);
            #pragma unroll
            for (int q = 0; q < 7; ++q) {
                const float2 v = xr[q];
                const int k = pp * F + q * 2;             // even
                const unsigned short h0 = f2bf(v.x), h1v = f2bf(v.y);
                const unsigned short l0 = f2bf(v.x - bf2f(h0)), l1 = f2bf(v.y - bf2f(h1v));
                const int off = (((k >> 5) * 4 + ((k >> 3) & 3)) * G + gl) * 8 + (k & 7);
                *reinterpret_cast<unsigned*>(&s_scr[off])         = (unsigned)h0 | ((unsigned)h1v << 16);
                *reinterpret_cast<unsigned*>(&s_scr[10240 + off]) = (unsigned)l0 | ((unsigned)l1 << 16);
            }
        }
    }
    __syncthreads();

    // ---- GEMM1: [32 x 308] x [308 x 256] ; wave wv owns cols [wv*64, wv*64+64) ----
    f32x4 acc[2][4];
    #pragma unroll
    for (int m = 0; m < 2; ++m)
        #pragma unroll
        for (int n = 0; n < 4; ++n) acc[m][n] = (f32x4){0.f, 0.f, 0.f, 0.f};

    {
        const unsigned short* B1h = ws + W1HI / 2;
        const unsigned short* B1l = ws + W1LO / 2;
        #pragma unroll 2
        for (int ks = 0; ks < KS1; ++ks) {
            bf16x8 ah[2], al[2];
            #pragma unroll
            for (int m = 0; m < 2; ++m) {
                const int ro = ((ks * 4 + kq) * G + (m * 16 + r16)) * 8;
                ah[m] = *reinterpret_cast<const bf16x8*>(&s_scr[ro]);
                al[m] = *reinterpret_cast<const bf16x8*>(&s_scr[10240 + ro]);
            }
            #pragma unroll
            for (int n = 0; n < 4; ++n) {
                const int bo = ((ks * JT1 + (wv * 4 + n)) * 64 + lane) * 8;
                const bf16x8 bh = *reinterpret_cast<const bf16x8*>(&B1h[bo]);
                const bf16x8 bl = *reinterpret_cast<const bf16x8*>(&B1l[bo]);
                #pragma unroll
                for (int m = 0; m < 2; ++m) {
                    acc[m][n] = __builtin_amdgcn_mfma_f32_16x16x32_bf16(ah[m], bh, acc[m][n], 0, 0, 0);
                    acc[m][n] = __builtin_amdgcn_mfma_f32_16x16x32_bf16(al[m], bh, acc[m][n], 0, 0, 0);
                    acc[m][n] = __builtin_amdgcn_mfma_f32_16x16x32_bf16(ah[m], bl, acc[m][n], 0, 0, 0);
                }
            }
        }
    }
    __syncthreads();   // A1 reads complete before A2 overwrites

    // epilogue 1: bias+relu, split, scatter into A2 tiled layout
    #pragma unroll
    for (int n = 0; n < 4; ++n) {
        const int j = (wv * 4 + n) * 16 + r16;            // h1 col = GEMM2 k index
        const float bb = s_b1[j];
        const int base = (((j >> 5) * 4 + ((j >> 3) & 3)) * G) * 8 + (j & 7);
        #pragma unroll
        for (int m = 0; m < 2; ++m) {
            #pragma unroll
            for (int r = 0; r < 4; ++r) {
                const int g = m * 16 + kq * 4 + r;        // C/D row = graph
                const float h = fmaxf(acc[m][n][r] + bb, 0.0f);
                const unsigned short hh = f2bf(h);
                const unsigned short ll = f2bf(h - bf2f(hh));
                const int off = base + g * 8;
                s_scr[off]        = hh;
                s_scr[8192 + off] = ll;
            }
        }
    }
    __syncthreads();

    // ---- GEMM2: [32 x 256] x [256 x 128] ; wave wv owns cols [wv*32, wv*32+32) ----
    f32x4 acc2[2][2];
    #pragma unroll
    for (int m = 0; m < 2; ++m)
        #pragma unroll
        for (int n = 0; n < 2; ++n) acc2[m][n] = (f32x4){0.f, 0.f, 0.f, 0.f};

    {
        const unsigned short* B2h = ws + W2HI / 2;
        const unsigned short* B2l = ws + W2LO / 2;
        #pragma unroll 2
        for (int ks = 0; ks < KS2; ++ks) {
            bf16x8 ah[2], al[2];
            #pragma unroll
            for (int m = 0; m < 2; ++m) {
                const int ro = ((ks * 4 + kq) * G + (m * 16 + r16)) * 8;
                ah[m] = *reinterpret_cast<const bf16x8*>(&s_scr[ro]);
                al[m] = *reinterpret_cast<const bf16x8*>(&s_scr[8192 + ro]);
            }
            #pragma unroll
            for (int n = 0; n < 2; ++n) {
                const int bo = ((ks * JT2 + (wv * 2 + n)) * 64 + lane) * 8;
                const bf16x8 bh = *reinterpret_cast<const bf16x8*>(&B2h[bo]);
                const bf16x8 bl = *reinterpret_cast<const bf16x8*>(&B2l[bo]);
                #pragma unroll
                for (int m = 0; m < 2; ++m) {
                    acc2[m][n] = __builtin_amdgcn_mfma_f32_16x16x32_bf16(ah[m], bh, acc2[m][n], 0, 0, 0);
                    acc2[m][n] = __builtin_amdgcn_mfma_f32_16x16x32_bf16(al[m], bh, acc2[m][n], 0, 0, 0);
                    acc2[m][n] = __builtin_amdgcn_mfma_f32_16x16x32_bf16(ah[m], bl, acc2[m][n], 0, 0, 0);
                }
            }
        }
    }
    __syncthreads();   // A2 reads complete before A3 write (A3 also overlaps old A1 bytes)

    // epilogue 2: bias+relu, split, scatter into A3
    #pragma unroll
    for (int n = 0; n < 2; ++n) {
        const int j = (wv * 2 + n) * 16 + r16;            // h2 col = GEMM3 k index, 0..127
        const float bb = s_b2[j];
        const int base = (((j >> 5) * 4 + ((j >> 3) & 3)) * G) * 8 + (j & 7);
        #pragma unroll
        for (int m = 0; m < 2; ++m) {
            #pragma unroll
            for (int r = 0; r < 4; ++r) {
                const int g = m * 16 + kq * 4 + r;
                const float h = fmaxf(acc2[m][n][r] + bb, 0.0f);
                const unsigned short hh = f2bf(h);
                const unsigned short ll = f2bf(h - bf2f(hh));
                const int off = base + g * 8;
                s_scr[16384 + off] = hh;
                s_scr[20480 + off] = ll;
            }
        }
    }
    __syncthreads();

    // ---- GEMM3: [32 x 128] x [128 x 22(pad 32)] ; waves 0,1 each take 16 graphs ----
    if (wv < 2) {
        f32x4 acc3[2];
        acc3[0] = (f32x4){0.f, 0.f, 0.f, 0.f};
        acc3[1] = (f32x4){0.f, 0.f, 0.f, 0.f};
        const unsigned short* B3h = ws + W3HI / 2;
        const unsigned short* B3l = ws + W3LO / 2;
        #pragma unroll
        for (int ks = 0; ks < KS3; ++ks) {
            const int ro = ((ks * 4 + kq) * G + (wv * 16 + r16)) * 8;
            const bf16x8 ah = *reinterpret_cast<const bf16x8*>(&s_scr[16384 + ro]);
            const bf16x8 al = *reinterpret_cast<const bf16x8*>(&s_scr[20480 + ro]);
            #pragma unroll
            for (int n = 0; n < 2; ++n) {
                const int bo = ((ks * JT3 + n) * 64 + lane) * 8;
                const bf16x8 bh = *reinterpret_cast<const bf16x8*>(&B3h[bo]);
                const bf16x8 bl = *reinterpret_cast<const bf16x8*>(&B3l[bo]);
                acc3[n] = __builtin_amdgcn_mfma_f32_16x16x32_bf16(ah, bh, acc3[n], 0, 0, 0);
                acc3[n] = __builtin_amdgcn_mfma_f32_16x16x32_bf16(al, bh, acc3[n], 0, 0, 0);
                acc3[n] = __builtin_amdgcn_mfma_f32_16x16x32_bf16(ah, bl, acc3[n], 0, 0, 0);
            }
        }
        #pragma unroll
        for (int n = 0; n < 2; ++n) {
            const int j = n * 16 + r16;
            if (j < P) {
                const float bb = s_b3[j];
                #pragma unroll
                for (int r = 0; r < 4; ++r) {
                    const int g = wv * 16 + kq * 4 + r;
                    out[(size_t)(g0 + g) * P + j] = acc3[n][r] + bb;
                }
            }
        }
    }
}

extern "C" void kernel_launch(void* const* d_in, const int* in_sizes, int n_in,
                              void* d_out, int out_size, void* d_ws, size_t ws_size,
                              hipStream_t stream) {
    const float* x     = (const float*)d_in[0];
    const int*   batch = (const int*)  d_in[1];
    const float* W1    = (const float*)d_in[2];
    const float* b1    = (const float*)d_in[3];
    const float* W2    = (const float*)d_in[4];
    const float* b2    = (const float*)d_in[5];
    const float* W3    = (const float*)d_in[6];
    const float* b3    = (const float*)d_in[7];
    float* out = (float*)d_out;

    convert_w_kernel<<<dim3((CVT_PAIRS + 255) / 256), dim3(256), 0, stream>>>(
        W1, W2, W3, (unsigned*)d_ws);
    mlp_mfma_kernel<<<dim3(NBLK), dim3(256), 0, stream>>>(
        x, batch, b1, b2, b3, (const unsigned short*)d_ws, out);
}

// Round 3
// 135.519 us; speedup vs baseline: 6.9539x; 1.0425x over previous
//
#include <hip/hip_runtime.h>
#include <hip/hip_fp16.h>

typedef __attribute__((ext_vector_type(8))) _Float16 half8;
typedef __attribute__((ext_vector_type(4))) float f32x4;

namespace {
constexpr int B_G = 131072;     // graphs
constexpr int P   = 22;
constexpr int F   = 14;
constexpr int NF  = 308;        // P*F
constexpr long long N_NODES = (long long)B_G * P;

constexpr int G    = 32;        // graphs per block
constexpr int NBLK = B_G / G;   // 4096

constexpr int KS1 = 10;         // ceil(308/32)
constexpr int KS2 = 8;          // 256/32
constexpr int KS3 = 4;          // 128/32
constexpr int JT1 = 16;         // 256/16
constexpr int JT2 = 8;          // 128/16
constexpr int JT3 = 2;          // 22 -> pad 32

// d_ws byte offsets; each fragment = 64 lanes * 16B = 1KB (fp16 now)
constexpr int W1HI = 0;
constexpr int W1LO = W1HI + KS1 * JT1 * 1024;
constexpr int W2HI = W1LO + KS1 * JT1 * 1024;
constexpr int W2LO = W2HI + KS2 * JT2 * 1024;
constexpr int W3HI = W2LO + KS2 * JT2 * 1024;
constexpr int W3LO = W3HI + KS3 * JT3 * 1024;
constexpr int CVT_PAIRS = (KS1*JT1 + KS2*JT2 + KS3*JT3) * 256;  // dwords
}

__device__ __forceinline__ unsigned short f2h(float v) {
    __half h = __float2half(v);
    return *reinterpret_cast<unsigned short*>(&h);
}
__device__ __forceinline__ float h2f(unsigned short u) {
    __half h;
    *reinterpret_cast<unsigned short*>(&h) = u;
    return __half2float(h);
}

// ---- one-time weight conversion: fp32 -> fp16 hi/lo, MFMA B-fragment order ----
__global__ void convert_w_kernel(const float* __restrict__ W1,
                                 const float* __restrict__ W2,
                                 const float* __restrict__ W3,
                                 unsigned* __restrict__ ws)
{
    int p = blockIdx.x * 256 + threadIdx.x;       // dword index (2 fp16 elems)
    if (p >= CVT_PAIRS) return;
    const int n1 = KS1 * JT1 * 256;
    const int n2 = KS2 * JT2 * 256;
    const float* W; int NK, NJ, stride, JT, hiB, loB, pl;
    if (p < n1)            { W = W1; NK = NF;  NJ = 256; stride = NF;  JT = JT1; hiB = W1HI/4; loB = W1LO/4; pl = p; }
    else if (p < n1 + n2)  { W = W2; NK = 256; NJ = 128; stride = 256; JT = JT2; hiB = W2HI/4; loB = W2LO/4; pl = p - n1; }
    else                   { W = W3; NK = 128; NJ = 22;  stride = 128; JT = JT3; hiB = W3HI/4; loB = W3LO/4; pl = p - n1 - n2; }

    const int e2   = pl & 3;
    const int lane = (pl >> 2) & 63;
    const int jt   = (pl >> 8) % JT;
    const int ks   = (pl >> 8) / JT;
    const int j    = jt * 16 + (lane & 15);
    const int kb   = ks * 32 + (lane >> 4) * 8 + e2 * 2;

    unsigned hi = 0, lo = 0;
    #pragma unroll
    for (int q = 0; q < 2; ++q) {
        const int k = kb + q;
        const float v = (k < NK && j < NJ) ? W[j * stride + k] : 0.0f;
        const unsigned short h = f2h(v);
        const unsigned short l = f2h(v - h2f(h));
        hi |= (unsigned)h << (16 * q);
        lo |= (unsigned)l << (16 * q);
    }
    ws[hiB + pl] = hi;
    ws[loB + pl] = lo;
}

// ---- fused: gather -> GEMM1 -> GEMM2 -> GEMM3 ; fp16 MFMA, weights 2-term ----
__global__ __launch_bounds__(256, 6)
void mlp_mfma_kernel(const float* __restrict__ x,
                     const int* __restrict__ batch,
                     const float* __restrict__ b1,
                     const float* __restrict__ b2,
                     const float* __restrict__ b3,
                     const unsigned short* __restrict__ ws,
                     float* __restrict__ out)
{
    // Activations fp16, tiled [ks][kq][graph G][e8]:
    // A1 = 10240 ush (k padded 308->320); A2 = 8192 ush @0; A3 = 4096 ush @0.
    __shared__ __align__(16) unsigned short s_scr[10240];   // 20480 B
    __shared__ float s_b1[256], s_b2[128], s_b3[32];
    __shared__ int s_start[G + 1];

    const int t    = threadIdx.x;
    const int g0   = blockIdx.x * G;
    const int lane = t & 63;
    const int wv   = t >> 6;          // 0..3
    const int r16  = lane & 15;
    const int kq   = lane >> 4;       // 0..3

    if (t < 256) s_b1[t] = b1[t];
    if (t < 128) s_b2[t] = b2[t];
    if (t < 32)  s_b3[t] = (t < 22) ? b3[t] : 0.0f;

    if (t <= G) {   // graph starts: windowed binary search + verified fallback
        const int target = g0 + t;
        long long wl = (long long)target * P - 5001; if (wl < 0) wl = 0;
        long long wh = (long long)target * P + 5001; if (wh > N_NODES) wh = N_NODES;
        int lo = (int)wl, hi = (int)wh;
        while (lo < hi) { int mid = (lo + hi) >> 1; if (batch[mid] < target) lo = mid + 1; else hi = mid; }
        const bool ok = (lo == 0 || batch[lo - 1] < target) &&
                        (lo == (int)N_NODES || batch[lo] >= target);
        if (!ok) {
            lo = 0; hi = (int)N_NODES;
            while (lo < hi) { int mid = (lo + hi) >> 1; if (batch[mid] < target) lo = mid + 1; else hi = mid; }
        }
        s_start[t] = lo;
    }

    for (int i = t; i < 1280; i += 256)   // pre-zero A1 (20480 B)
        reinterpret_cast<uint4*>(s_scr)[i] = make_uint4(0u, 0u, 0u, 0u);
    __syncthreads();

    // ---- gather + fp32->fp16 into tiled LDS ----
    const int s0 = s_start[0], s1 = s_start[G];
    for (int i = s0 + t; i < s1; i += 256) {
        const int gl = batch[i] - g0;
        const int pp = i - s_start[gl];
        if (pp < P) {
            const float2* xr = reinterpret_cast<const float2*>(x + (size_t)i * F);
            #pragma unroll
            for (int q = 0; q < 7; ++q) {
                const float2 v = xr[q];
                const int k = pp * F + q * 2;             // even
                const unsigned d = (unsigned)f2h(v.x) | ((unsigned)f2h(v.y) << 16);
                const int off = (((k >> 5) * 4 + ((k >> 3) & 3)) * G + gl) * 8 + (k & 7);
                *reinterpret_cast<unsigned*>(&s_scr[off]) = d;
            }
        }
    }
    __syncthreads();

    // ---- GEMM1: [32 x 308] x [308 x 256]; wave owns cols [wv*64, wv*64+64) ----
    f32x4 acc[2][4];
    #pragma unroll
    for (int m = 0; m < 2; ++m)
        #pragma unroll
        for (int n = 0; n < 4; ++n) acc[m][n] = (f32x4){0.f, 0.f, 0.f, 0.f};

    {
        const unsigned short* B1h = ws + W1HI / 2;
        const unsigned short* B1l = ws + W1LO / 2;
        #pragma unroll 2
        for (int ks = 0; ks < KS1; ++ks) {
            half8 a[2];
            #pragma unroll
            for (int m = 0; m < 2; ++m)
                a[m] = *reinterpret_cast<const half8*>(&s_scr[((ks * 4 + kq) * G + (m * 16 + r16)) * 8]);
            #pragma unroll
            for (int n = 0; n < 4; ++n) {
                const int bo = ((ks * JT1 + (wv * 4 + n)) * 64 + lane) * 8;
                const half8 bh = *reinterpret_cast<const half8*>(&B1h[bo]);
                const half8 bl = *reinterpret_cast<const half8*>(&B1l[bo]);
                #pragma unroll
                for (int m = 0; m < 2; ++m) {
                    acc[m][n] = __builtin_amdgcn_mfma_f32_16x16x32_f16(a[m], bh, acc[m][n], 0, 0, 0);
                    acc[m][n] = __builtin_amdgcn_mfma_f32_16x16x32_f16(a[m], bl, acc[m][n], 0, 0, 0);
                }
            }
        }
    }
    __syncthreads();   // A1 reads done before A2 overwrite

    // epilogue 1: bias+relu -> fp16 -> A2 tiled
    #pragma unroll
    for (int n = 0; n < 4; ++n) {
        const int j = (wv * 4 + n) * 16 + r16;            // h1 col = GEMM2 k
        const float bb = s_b1[j];
        const int base = (((j >> 5) * 4 + ((j >> 3) & 3)) * G) * 8 + (j & 7);
        #pragma unroll
        for (int m = 0; m < 2; ++m)
            #pragma unroll
            for (int r = 0; r < 4; ++r) {
                const int g = m * 16 + kq * 4 + r;
                s_scr[base + g * 8] = f2h(fmaxf(acc[m][n][r] + bb, 0.0f));
            }
    }
    __syncthreads();

    // ---- GEMM2: [32 x 256] x [256 x 128]; wave owns cols [wv*32, wv*32+32) ----
    f32x4 acc2[2][2];
    #pragma unroll
    for (int m = 0; m < 2; ++m)
        #pragma unroll
        for (int n = 0; n < 2; ++n) acc2[m][n] = (f32x4){0.f, 0.f, 0.f, 0.f};

    {
        const unsigned short* B2h = ws + W2HI / 2;
        const unsigned short* B2l = ws + W2LO / 2;
        #pragma unroll 2
        for (int ks = 0; ks < KS2; ++ks) {
            half8 a[2];
            #pragma unroll
            for (int m = 0; m < 2; ++m)
                a[m] = *reinterpret_cast<const half8*>(&s_scr[((ks * 4 + kq) * G + (m * 16 + r16)) * 8]);
            #pragma unroll
            for (int n = 0; n < 2; ++n) {
                const int bo = ((ks * JT2 + (wv * 2 + n)) * 64 + lane) * 8;
                const half8 bh = *reinterpret_cast<const half8*>(&B2h[bo]);
                const half8 bl = *reinterpret_cast<const half8*>(&B2l[bo]);
                #pragma unroll
                for (int m = 0; m < 2; ++m) {
                    acc2[m][n] = __builtin_amdgcn_mfma_f32_16x16x32_f16(a[m], bh, acc2[m][n], 0, 0, 0);
                    acc2[m][n] = __builtin_amdgcn_mfma_f32_16x16x32_f16(a[m], bl, acc2[m][n], 0, 0, 0);
                }
            }
        }
    }
    __syncthreads();   // A2 reads done before A3 overwrite

    // epilogue 2: bias+relu -> fp16 -> A3 tiled
    #pragma unroll
    for (int n = 0; n < 2; ++n) {
        const int j = (wv * 2 + n) * 16 + r16;            // h2 col = GEMM3 k (0..127)
        const float bb = s_b2[j];
        const int base = (((j >> 5) * 4 + ((j >> 3) & 3)) * G) * 8 + (j & 7);
        #pragma unroll
        for (int m = 0; m < 2; ++m)
            #pragma unroll
            for (int r = 0; r < 4; ++r) {
                const int g = m * 16 + kq * 4 + r;
                s_scr[base + g * 8] = f2h(fmaxf(acc2[m][n][r] + bb, 0.0f));
            }
    }
    __syncthreads();

    // ---- GEMM3: [32 x 128] x [128 x 22(pad32)]; waves 0,1 take 16 graphs each ----
    if (wv < 2) {
        f32x4 acc3[2];
        acc3[0] = (f32x4){0.f, 0.f, 0.f, 0.f};
        acc3[1] = (f32x4){0.f, 0.f, 0.f, 0.f};
        const unsigned short* B3h = ws + W3HI / 2;
        const unsigned short* B3l = ws + W3LO / 2;
        #pragma unroll
        for (int ks = 0; ks < KS3; ++ks) {
            const half8 a = *reinterpret_cast<const half8*>(&s_scr[((ks * 4 + kq) * G + (wv * 16 + r16)) * 8]);
            #pragma unroll
            for (int n = 0; n < 2; ++n) {
                const int bo = ((ks * JT3 + n) * 64 + lane) * 8;
                const half8 bh = *reinterpret_cast<const half8*>(&B3h[bo]);
                const half8 bl = *reinterpret_cast<const half8*>(&B3l[bo]);
                acc3[n] = __builtin_amdgcn_mfma_f32_16x16x32_f16(a, bh, acc3[n], 0, 0, 0);
                acc3[n] = __builtin_amdgcn_mfma_f32_16x16x32_f16(a, bl, acc3[n], 0, 0, 0);
            }
        }
        #pragma unroll
        for (int n = 0; n < 2; ++n) {
            const int j = n * 16 + r16;
            if (j < P) {
                const float bb = s_b3[j];
                #pragma unroll
                for (int r = 0; r < 4; ++r) {
                    const int g = wv * 16 + kq * 4 + r;
                    out[(size_t)(g0 + g) * P + j] = acc3[n][r] + bb;
                }
            }
        }
    }
}

extern "C" void kernel_launch(void* const* d_in, const int* in_sizes, int n_in,
                              void* d_out, int out_size, void* d_ws, size_t ws_size,
                              hipStream_t stream) {
    const float* x     = (const float*)d_in[0];
    const int*   batch = (const int*)  d_in[1];
    const float* W1    = (const float*)d_in[2];
    const float* b1    = (const float*)d_in[3];
    const float* W2    = (const float*)d_in[4];
    const float* b2    = (const float*)d_in[5];
    const float* W3    = (const float*)d_in[6];
    const float* b3    = (const float*)d_in[7];
    float* out = (float*)d_out;

    convert_w_kernel<<<dim3((CVT_PAIRS + 255) / 256), dim3(256), 0, stream>>>(
        W1, W2, W3, (unsigned*)d_ws);
    mlp_mfma_kernel<<<dim3(NBLK), dim3(256), 0, stream>>>(
        x, batch, b1, b2, b3, (const unsigned short*)d_ws, out);
}

// Round 5
// 94.443 us; speedup vs baseline: 9.9784x; 1.4349x over previous
//
#include <hip/hip_runtime.h>
#include <hip/hip_fp16.h>

typedef __attribute__((ext_vector_type(8))) _Float16 half8;
typedef __attribute__((ext_vector_type(4))) float f32x4;

namespace {
constexpr int B_G = 131072;     // graphs
constexpr int P   = 22;
constexpr int F   = 14;
constexpr int NF  = 308;        // P*F
constexpr long long N_NODES = (long long)B_G * P;

constexpr int G    = 64;        // graphs per block
constexpr int NBLK = B_G / G;   // 2048

constexpr int KS1 = 10;         // ceil(308/32)
constexpr int KS2 = 8;          // 256/32
constexpr int KS3 = 4;          // 128/32
constexpr int JT1 = 16;         // 256/16
constexpr int JT2 = 8;          // 128/16
constexpr int JT3 = 2;          // 22 -> pad 32

// d_ws byte offsets; each fragment = 64 lanes * 16B = 1KB (fp16)
constexpr int W1HI = 0;
constexpr int W1LO = W1HI + KS1 * JT1 * 1024;
constexpr int W2HI = W1LO + KS1 * JT1 * 1024;
constexpr int W2LO = W2HI + KS2 * JT2 * 1024;
constexpr int W3HI = W2LO + KS2 * JT2 * 1024;
constexpr int W3LO = W3HI + KS3 * JT3 * 1024;
constexpr int CVT_PAIRS = (KS1*JT1 + KS2*JT2 + KS3*JT3) * 256;  // dwords
}

__device__ __forceinline__ unsigned short f2h(float v) {
    __half h = __float2half(v);
    return *reinterpret_cast<unsigned short*>(&h);
}
__device__ __forceinline__ float h2f(unsigned short u) {
    __half h;
    *reinterpret_cast<unsigned short*>(&h) = u;
    return __half2float(h);
}

// ---- one-time weight conversion: fp32 -> fp16 hi/lo, MFMA B-fragment order ----
__global__ void convert_w_kernel(const float* __restrict__ W1,
                                 const float* __restrict__ W2,
                                 const float* __restrict__ W3,
                                 unsigned* __restrict__ ws)
{
    int p = blockIdx.x * 256 + threadIdx.x;       // dword index (2 fp16 elems)
    if (p >= CVT_PAIRS) return;
    const int n1 = KS1 * JT1 * 256;
    const int n2 = KS2 * JT2 * 256;
    const float* W; int NK, NJ, stride, JT, hiB, loB, pl;
    if (p < n1)            { W = W1; NK = NF;  NJ = 256; stride = NF;  JT = JT1; hiB = W1HI/4; loB = W1LO/4; pl = p; }
    else if (p < n1 + n2)  { W = W2; NK = 256; NJ = 128; stride = 256; JT = JT2; hiB = W2HI/4; loB = W2LO/4; pl = p - n1; }
    else                   { W = W3; NK = 128; NJ = 22;  stride = 128; JT = JT3; hiB = W3HI/4; loB = W3LO/4; pl = p - n1 - n2; }

    const int e2   = pl & 3;
    const int lane = (pl >> 2) & 63;
    const int jt   = (pl >> 8) % JT;
    const int ks   = (pl >> 8) / JT;
    const int j    = jt * 16 + (lane & 15);
    const int kb   = ks * 32 + (lane >> 4) * 8 + e2 * 2;

    unsigned hi = 0, lo = 0;
    #pragma unroll
    for (int q = 0; q < 2; ++q) {
        const int k = kb + q;
        const float v = (k < NK && j < NJ) ? W[j * stride + k] : 0.0f;
        const unsigned short h = f2h(v);
        const unsigned short l = f2h(v - h2f(h));
        hi |= (unsigned)h << (16 * q);
        lo |= (unsigned)l << (16 * q);
    }
    ws[hiB + pl] = hi;
    ws[loB + pl] = lo;
}

#define MFMA16(A_, B_, C_) __builtin_amdgcn_mfma_f32_16x16x32_f16(A_, B_, C_, 0, 0, 0)

// B-fragment load, GEMM1 (4 n-tiles): hi+lo into named register sets
#define LOADB1(H_, L_, KS_) { \
    _Pragma("unroll") for (int n = 0; n < 4; ++n) { \
        const int bo = (((KS_) * JT1 + (wv * 4 + n)) * 64 + lane) * 8; \
        H_[n] = *reinterpret_cast<const half8*>(&B1h[bo]); \
        L_[n] = *reinterpret_cast<const half8*>(&B1l[bo]); } }

#define COMP1(H_, L_, KS_) { \
    half8 a_[4]; \
    _Pragma("unroll") for (int m = 0; m < 4; ++m) \
        a_[m] = *reinterpret_cast<const half8*>(&s_scr[(((KS_) * 4 + kq) * G + (m * 16 + r16)) * 8]); \
    _Pragma("unroll") for (int n = 0; n < 4; ++n) \
        _Pragma("unroll") for (int m = 0; m < 4; ++m) { \
            acc[m][n] = MFMA16(a_[m], H_[n], acc[m][n]); \
            acc[m][n] = MFMA16(a_[m], L_[n], acc[m][n]); } }

#define LOADB2(H_, L_, KS_) { \
    _Pragma("unroll") for (int n = 0; n < 2; ++n) { \
        const int bo = (((KS_) * JT2 + (wv * 2 + n)) * 64 + lane) * 8; \
        H_[n] = *reinterpret_cast<const half8*>(&B2h[bo]); \
        L_[n] = *reinterpret_cast<const half8*>(&B2l[bo]); } }

#define COMP2(H_, L_, KS_) { \
    half8 a_[4]; \
    _Pragma("unroll") for (int m = 0; m < 4; ++m) \
        a_[m] = *reinterpret_cast<const half8*>(&s_scr[(((KS_) * 4 + kq) * G + (m * 16 + r16)) * 8]); \
    _Pragma("unroll") for (int n = 0; n < 2; ++n) \
        _Pragma("unroll") for (int m = 0; m < 4; ++m) { \
            acc2[m][n] = MFMA16(a_[m], H_[n], acc2[m][n]); \
            acc2[m][n] = MFMA16(a_[m], L_[n], acc2[m][n]); } }

// ---- fused: gather -> GEMM1 -> GEMM2 -> GEMM3 ; fp16 MFMA, 2-term weights ----
__global__ __launch_bounds__(256, 3)
void mlp_mfma_kernel(const float* __restrict__ x,
                     const int* __restrict__ batch,
                     const float* __restrict__ b1,
                     const float* __restrict__ b2,
                     const float* __restrict__ b3,
                     const unsigned short* __restrict__ ws,
                     float* __restrict__ out)
{
    // Activations fp16, tiled [ks][kq][graph G][e8]:
    // A1 = 20480 ush @0 (k 308->320); A2 = 16384 ush @0; A3 = 8192 ush @16384.
    // s_scr must cover A3 end = 16384 + 4*4*G*8 = 24576 ush.  (round-4 bug: was 20480 -> OOB)
    __shared__ __align__(16) unsigned short s_scr[24576];   // 49152 B
    __shared__ float s_b1[256], s_b2[128], s_b3[32];
    __shared__ int s_start[G + 1];

    const int t    = threadIdx.x;
    const int g0   = blockIdx.x * G;
    const int lane = t & 63;
    const int wv   = t >> 6;          // 0..3
    const int r16  = lane & 15;
    const int kq   = lane >> 4;       // 0..3

    if (t < 256) s_b1[t] = b1[t];
    if (t < 128) s_b2[t] = b2[t];
    if (t < 32)  s_b3[t] = (t < 22) ? b3[t] : 0.0f;

    if (t <= G) {   // graph starts: windowed binary search + verified fallback
        const int target = g0 + t;
        long long wl = (long long)target * P - 5001; if (wl < 0) wl = 0;
        long long wh = (long long)target * P + 5001; if (wh > N_NODES) wh = N_NODES;
        int lo = (int)wl, hi = (int)wh;
        while (lo < hi) { int mid = (lo + hi) >> 1; if (batch[mid] < target) lo = mid + 1; else hi = mid; }
        const bool ok = (lo == 0 || batch[lo - 1] < target) &&
                        (lo == (int)N_NODES || batch[lo] >= target);
        if (!ok) {
            lo = 0; hi = (int)N_NODES;
            while (lo < hi) { int mid = (lo + hi) >> 1; if (batch[mid] < target) lo = mid + 1; else hi = mid; }
        }
        s_start[t] = lo;
    }

    for (int i = t; i < 2560; i += 256)   // pre-zero A1 (40960 B)
        reinterpret_cast<uint4*>(s_scr)[i] = make_uint4(0u, 0u, 0u, 0u);
    __syncthreads();

    // ---- gather + fp32->fp16 into tiled LDS ----
    const int s0 = s_start[0], s1 = s_start[G];
    for (int i = s0 + t; i < s1; i += 256) {
        const int gl = batch[i] - g0;
        const int pp = i - s_start[gl];
        if (pp < P) {
            const float2* xr = reinterpret_cast<const float2*>(x + (size_t)i * F);
            #pragma unroll
            for (int q = 0; q < 7; ++q) {
                const float2 v = xr[q];
                const int k = pp * F + q * 2;             // even
                const unsigned d = (unsigned)f2h(v.x) | ((unsigned)f2h(v.y) << 16);
                const int off = (((k >> 5) * 4 + ((k >> 3) & 3)) * G + gl) * 8 + (k & 7);
                *reinterpret_cast<unsigned*>(&s_scr[off]) = d;
            }
        }
    }

    const unsigned short* B1h = ws + W1HI / 2;
    const unsigned short* B1l = ws + W1LO / 2;
    half8 bha[4], bla[4], bhb[4], blb[4];
    LOADB1(bha, bla, 0)                 // prefetch stage 0 under the barrier
    __syncthreads();

    // ---- GEMM1: [64 x 308] x [308 x 256]; wave owns cols [wv*64, +64) ----
    f32x4 acc[4][4];
    #pragma unroll
    for (int m = 0; m < 4; ++m)
        #pragma unroll
        for (int n = 0; n < 4; ++n) acc[m][n] = (f32x4){0.f, 0.f, 0.f, 0.f};

    LOADB1(bhb, blb, 1)  COMP1(bha, bla, 0)
    LOADB1(bha, bla, 2)  COMP1(bhb, blb, 1)
    LOADB1(bhb, blb, 3)  COMP1(bha, bla, 2)
    LOADB1(bha, bla, 4)  COMP1(bhb, blb, 3)
    LOADB1(bhb, blb, 5)  COMP1(bha, bla, 4)
    LOADB1(bha, bla, 6)  COMP1(bhb, blb, 5)
    LOADB1(bhb, blb, 7)  COMP1(bha, bla, 6)
    LOADB1(bha, bla, 8)  COMP1(bhb, blb, 7)
    LOADB1(bhb, blb, 9)  COMP1(bha, bla, 8)
    COMP1(bhb, blb, 9)
    __syncthreads();   // A1 reads done before A2 overwrite

    // epilogue 1: bias+relu -> fp16 -> A2 tiled
    #pragma unroll
    for (int n = 0; n < 4; ++n) {
        const int j = (wv * 4 + n) * 16 + r16;            // h1 col = GEMM2 k
        const float bb = s_b1[j];
        const int base = (((j >> 5) * 4 + ((j >> 3) & 3)) * G) * 8 + (j & 7);
        #pragma unroll
        for (int m = 0; m < 4; ++m)
            #pragma unroll
            for (int r = 0; r < 4; ++r) {
                const int g = m * 16 + kq * 4 + r;
                s_scr[base + g * 8] = f2h(fmaxf(acc[m][n][r] + bb, 0.0f));
            }
    }
    __syncthreads();

    // ---- GEMM2: [64 x 256] x [256 x 128]; wave owns cols [wv*32, +32) ----
    const unsigned short* B2h = ws + W2HI / 2;
    const unsigned short* B2l = ws + W2LO / 2;
    f32x4 acc2[4][2];
    #pragma unroll
    for (int m = 0; m < 4; ++m)
        #pragma unroll
        for (int n = 0; n < 2; ++n) acc2[m][n] = (f32x4){0.f, 0.f, 0.f, 0.f};

    half8 ch_a[2], cl_a[2], ch_b[2], cl_b[2];
    LOADB2(ch_a, cl_a, 0)
    LOADB2(ch_b, cl_b, 1)  COMP2(ch_a, cl_a, 0)
    LOADB2(ch_a, cl_a, 2)  COMP2(ch_b, cl_b, 1)
    LOADB2(ch_b, cl_b, 3)  COMP2(ch_a, cl_a, 2)
    LOADB2(ch_a, cl_a, 4)  COMP2(ch_b, cl_b, 3)
    LOADB2(ch_b, cl_b, 5)  COMP2(ch_a, cl_a, 4)
    LOADB2(ch_a, cl_a, 6)  COMP2(ch_b, cl_b, 5)
    LOADB2(ch_b, cl_b, 7)  COMP2(ch_a, cl_a, 6)
    COMP2(ch_b, cl_b, 7)

    // epilogue 2: bias+relu -> fp16 -> A3 @16384 (disjoint from A2 0..16383: no barrier before writes)
    #pragma unroll
    for (int n = 0; n < 2; ++n) {
        const int j = (wv * 2 + n) * 16 + r16;            // h2 col = GEMM3 k (0..127)
        const float bb = s_b2[j];
        const int base = 16384 + (((j >> 5) * 4 + ((j >> 3) & 3)) * G) * 8 + (j & 7);
        #pragma unroll
        for (int m = 0; m < 4; ++m)
            #pragma unroll
            for (int r = 0; r < 4; ++r) {
                const int g = m * 16 + kq * 4 + r;
                s_scr[base + g * 8] = f2h(fmaxf(acc2[m][n][r] + bb, 0.0f));
            }
    }
    __syncthreads();

    // ---- GEMM3: [64 x 128] x [128 x 22(pad32)]; wave wv owns graphs [wv*16, +16) ----
    {
        f32x4 acc3[2];
        acc3[0] = (f32x4){0.f, 0.f, 0.f, 0.f};
        acc3[1] = (f32x4){0.f, 0.f, 0.f, 0.f};
        const unsigned short* B3h = ws + W3HI / 2;
        const unsigned short* B3l = ws + W3LO / 2;
        #pragma unroll
        for (int ks = 0; ks < KS3; ++ks) {
            const half8 a = *reinterpret_cast<const half8*>(
                &s_scr[16384 + ((ks * 4 + kq) * G + (wv * 16 + r16)) * 8]);
            #pragma unroll
            for (int n = 0; n < 2; ++n) {
                const int bo = ((ks * JT3 + n) * 64 + lane) * 8;
                const half8 bh = *reinterpret_cast<const half8*>(&B3h[bo]);
                const half8 bl = *reinterpret_cast<const half8*>(&B3l[bo]);
                acc3[n] = MFMA16(a, bh, acc3[n]);
                acc3[n] = MFMA16(a, bl, acc3[n]);
            }
        }
        #pragma unroll
        for (int n = 0; n < 2; ++n) {
            const int j = n * 16 + r16;
            if (j < P) {
                const float bb = s_b3[j];
                #pragma unroll
                for (int r = 0; r < 4; ++r) {
                    const int g = wv * 16 + kq * 4 + r;
                    out[(size_t)(g0 + g) * P + j] = acc3[n][r] + bb;
                }
            }
        }
    }
}

extern "C" void kernel_launch(void* const* d_in, const int* in_sizes, int n_in,
                              void* d_out, int out_size, void* d_ws, size_t ws_size,
                              hipStream_t stream) {
    const float* x     = (const float*)d_in[0];
    const int*   batch = (const int*)  d_in[1];
    const float* W1    = (const float*)d_in[2];
    const float* b1    = (const float*)d_in[3];
    const float* W2    = (const float*)d_in[4];
    const float* b2    = (const float*)d_in[5];
    const float* W3    = (const float*)d_in[6];
    const float* b3    = (const float*)d_in[7];
    float* out = (float*)d_out;

    convert_w_kernel<<<dim3((CVT_PAIRS + 255) / 256), dim3(256), 0, stream>>>(
        W1, W2, W3, (unsigned*)d_ws);
    mlp_mfma_kernel<<<dim3(NBLK), dim3(256), 0, stream>>>(
        x, batch, b1, b2, b3, (const unsigned short*)d_ws, out);
}

// Round 6
// 69.372 us; speedup vs baseline: 13.5845x; 1.3614x over previous
//
#include <hip/hip_runtime.h>
#include <hip/hip_fp16.h>

typedef __attribute__((ext_vector_type(8))) _Float16 half8;
typedef __attribute__((ext_vector_type(4))) float f32x4;

namespace {
constexpr int B_G = 131072;     // graphs
constexpr int P   = 22;
constexpr int F   = 14;
constexpr int NF  = 308;        // P*F
constexpr long long N_NODES = (long long)B_G * P;

constexpr int G    = 64;        // graphs per block
constexpr int NBLK = B_G / G;   // 2048

constexpr int KS1 = 10;         // ceil(308/32)
constexpr int KS2 = 8;          // 256/32
constexpr int KS3 = 4;          // 128/32
constexpr int JT1 = 16;         // 256/16
constexpr int JT2 = 8;          // 128/16
constexpr int JT3 = 2;          // 22 -> pad 32

// d_ws byte offsets; single-term fp16 weights, MFMA B-fragment order (1KB/fragment)
constexpr int W1F = 0;
constexpr int W2F = W1F + KS1 * JT1 * 1024;   // 163840
constexpr int W3F = W2F + KS2 * JT2 * 1024;   // 229376
constexpr int CVT_DWORDS = (KS1*JT1 + KS2*JT2 + KS3*JT3) * 256;  // 59392
}

__device__ __forceinline__ unsigned short f2h(float v) {
    __half h = __float2half(v);
    return *reinterpret_cast<unsigned short*>(&h);
}

// ---- one-time weight conversion: fp32 -> fp16 (single term), MFMA B-fragment order ----
__global__ void convert_w_kernel(const float* __restrict__ W1,
                                 const float* __restrict__ W2,
                                 const float* __restrict__ W3,
                                 unsigned* __restrict__ ws)
{
    int p = blockIdx.x * 256 + threadIdx.x;       // dword index (2 fp16 elems)
    if (p >= CVT_DWORDS) return;
    const int n1 = KS1 * JT1 * 256;
    const int n2 = KS2 * JT2 * 256;
    const float* W; int NK, NJ, stride, JT, oB, pl;
    if (p < n1)            { W = W1; NK = NF;  NJ = 256; stride = NF;  JT = JT1; oB = W1F/4; pl = p; }
    else if (p < n1 + n2)  { W = W2; NK = 256; NJ = 128; stride = 256; JT = JT2; oB = W2F/4; pl = p - n1; }
    else                   { W = W3; NK = 128; NJ = 22;  stride = 128; JT = JT3; oB = W3F/4; pl = p - n1 - n2; }

    const int e2   = pl & 3;
    const int lane = (pl >> 2) & 63;
    const int jt   = (pl >> 8) % JT;
    const int ks   = (pl >> 8) / JT;
    const int j    = jt * 16 + (lane & 15);
    const int kb   = ks * 32 + (lane >> 4) * 8 + e2 * 2;

    unsigned d = 0;
    #pragma unroll
    for (int q = 0; q < 2; ++q) {
        const int k = kb + q;
        const float v = (k < NK && j < NJ) ? W[j * stride + k] : 0.0f;
        d |= (unsigned)f2h(v) << (16 * q);
    }
    ws[oB + pl] = d;
}

#define MFMA16(A_, B_, C_) __builtin_amdgcn_mfma_f32_16x16x32_f16(A_, B_, C_, 0, 0, 0)

#define LOADB1(H_, KS_) { \
    _Pragma("unroll") for (int n = 0; n < 4; ++n) \
        H_[n] = *reinterpret_cast<const half8*>(&B1[((((KS_) * JT1) + (wv * 4 + n)) * 64 + lane) * 8]); }

#define COMP1(H_, KS_) { \
    half8 a_[4]; \
    _Pragma("unroll") for (int m = 0; m < 4; ++m) \
        a_[m] = *reinterpret_cast<const half8*>(&s_scr[(((KS_) * 4 + kq) * G + (m * 16 + r16)) * 8]); \
    _Pragma("unroll") for (int n = 0; n < 4; ++n) \
        _Pragma("unroll") for (int m = 0; m < 4; ++m) \
            acc[m][n] = MFMA16(a_[m], H_[n], acc[m][n]); }

#define LOADB2(H_, KS_) { \
    _Pragma("unroll") for (int n = 0; n < 2; ++n) \
        H_[n] = *reinterpret_cast<const half8*>(&B2[((((KS_) * JT2) + (wv * 2 + n)) * 64 + lane) * 8]); }

#define COMP2(H_, KS_) { \
    half8 a_[4]; \
    _Pragma("unroll") for (int m = 0; m < 4; ++m) \
        a_[m] = *reinterpret_cast<const half8*>(&s_scr[(((KS_) * 4 + kq) * G + (m * 16 + r16)) * 8]); \
    _Pragma("unroll") for (int n = 0; n < 2; ++n) \
        _Pragma("unroll") for (int m = 0; m < 4; ++m) \
            acc2[m][n] = MFMA16(a_[m], H_[n], acc2[m][n]); }

// ---- fused: gather -> GEMM1 -> GEMM2 -> GEMM3 ; fp16 MFMA, single-term weights ----
__global__ __launch_bounds__(256, 3)
void mlp_mfma_kernel(const float* __restrict__ x,
                     const int* __restrict__ batch,
                     const float* __restrict__ b1,
                     const float* __restrict__ b2,
                     const float* __restrict__ b3,
                     const unsigned short* __restrict__ ws,
                     float* __restrict__ out)
{
    // Activations fp16, tiled [ks][kq][graph G][e8]:
    // A1 = 20480 ush @0 (k 308->320); A2 = 16384 ush @0; A3 = 8192 ush @16384 (end 24576).
    __shared__ __align__(16) unsigned short s_scr[24576];   // 49152 B
    __shared__ float s_b1[256], s_b2[128], s_b3[32];
    __shared__ int s_start[G + 1];

    const int t    = threadIdx.x;
    const int g0   = blockIdx.x * G;
    const int lane = t & 63;
    const int wv   = t >> 6;          // 0..3
    const int r16  = lane & 15;
    const int kq   = lane >> 4;       // 0..3

    if (t < 256) s_b1[t] = b1[t];
    if (t < 128) s_b2[t] = b2[t];
    if (t < 32)  s_b3[t] = (t < 22) ? b3[t] : 0.0f;

    if (t <= G) {   // graph starts: windowed binary search + verified fallback
        const int target = g0 + t;
        long long wl = (long long)target * P - 5001; if (wl < 0) wl = 0;
        long long wh = (long long)target * P + 5001; if (wh > N_NODES) wh = N_NODES;
        int lo = (int)wl, hi = (int)wh;
        while (lo < hi) { int mid = (lo + hi) >> 1; if (batch[mid] < target) lo = mid + 1; else hi = mid; }
        const bool ok = (lo == 0 || batch[lo - 1] < target) &&
                        (lo == (int)N_NODES || batch[lo] >= target);
        if (!ok) {
            lo = 0; hi = (int)N_NODES;
            while (lo < hi) { int mid = (lo + hi) >> 1; if (batch[mid] < target) lo = mid + 1; else hi = mid; }
        }
        s_start[t] = lo;
    }

    for (int i = t; i < 2560; i += 256)   // pre-zero A1 (40960 B)
        reinterpret_cast<uint4*>(s_scr)[i] = make_uint4(0u, 0u, 0u, 0u);
    __syncthreads();

    // ---- gather + fp32->fp16 into tiled LDS ----
    const int s0 = s_start[0], s1 = s_start[G];
    for (int i = s0 + t; i < s1; i += 256) {
        const int gl = batch[i] - g0;
        const int pp = i - s_start[gl];
        if (pp < P) {
            const float2* xr = reinterpret_cast<const float2*>(x + (size_t)i * F);
            #pragma unroll
            for (int q = 0; q < 7; ++q) {
                const float2 v = xr[q];
                const int k = pp * F + q * 2;             // even
                const unsigned d = (unsigned)f2h(v.x) | ((unsigned)f2h(v.y) << 16);
                const int off = (((k >> 5) * 4 + ((k >> 3) & 3)) * G + gl) * 8 + (k & 7);
                *reinterpret_cast<unsigned*>(&s_scr[off]) = d;
            }
        }
    }

    const unsigned short* B1 = ws + W1F / 2;
    const unsigned short* B2 = ws + W2F / 2;
    const unsigned short* B3 = ws + W3F / 2;

    half8 Ba[4], Bb[4], Bc[4];
    LOADB1(Ba, 0)                 // prefetch stages 0,1 under the barrier
    LOADB1(Bb, 1)
    __syncthreads();

    // ---- GEMM1: [64 x 308] x [308 x 256]; wave owns cols [wv*64, +64); depth-2 pipeline ----
    f32x4 acc[4][4];
    #pragma unroll
    for (int m = 0; m < 4; ++m)
        #pragma unroll
        for (int n = 0; n < 4; ++n) acc[m][n] = (f32x4){0.f, 0.f, 0.f, 0.f};

    LOADB1(Bc, 2)  COMP1(Ba, 0)
    LOADB1(Ba, 3)  COMP1(Bb, 1)
    LOADB1(Bb, 4)  COMP1(Bc, 2)
    LOADB1(Bc, 5)  COMP1(Ba, 3)
    LOADB1(Ba, 6)  COMP1(Bb, 4)
    LOADB1(Bb, 7)  COMP1(Bc, 5)
    LOADB1(Bc, 8)  COMP1(Ba, 6)
    LOADB1(Ba, 9)  COMP1(Bb, 7)
    COMP1(Bc, 8)

    half8 Ca[2], Cb[2], Cc[2];
    LOADB2(Ca, 0)                 // GEMM2 stages 0,1 hide under epilogue 1
    LOADB2(Cb, 1)
    COMP1(Ba, 9)
    __syncthreads();   // A1 reads done before A2 overwrite

    // epilogue 1: bias+relu -> fp16 -> A2 tiled
    #pragma unroll
    for (int n = 0; n < 4; ++n) {
        const int j = (wv * 4 + n) * 16 + r16;            // h1 col = GEMM2 k
        const float bb = s_b1[j];
        const int base = (((j >> 5) * 4 + ((j >> 3) & 3)) * G) * 8 + (j & 7);
        #pragma unroll
        for (int m = 0; m < 4; ++m)
            #pragma unroll
            for (int r = 0; r < 4; ++r) {
                const int g = m * 16 + kq * 4 + r;
                s_scr[base + g * 8] = f2h(fmaxf(acc[m][n][r] + bb, 0.0f));
            }
    }
    __syncthreads();

    // ---- GEMM2: [64 x 256] x [256 x 128]; wave owns cols [wv*32, +32); depth-2 ----
    f32x4 acc2[4][2];
    #pragma unroll
    for (int m = 0; m < 4; ++m)
        #pragma unroll
        for (int n = 0; n < 2; ++n) acc2[m][n] = (f32x4){0.f, 0.f, 0.f, 0.f};

    LOADB2(Cc, 2)  COMP2(Ca, 0)
    LOADB2(Ca, 3)  COMP2(Cb, 1)
    LOADB2(Cb, 4)  COMP2(Cc, 2)
    LOADB2(Cc, 5)  COMP2(Ca, 3)
    LOADB2(Ca, 6)  COMP2(Cb, 4)
    LOADB2(Cb, 7)  COMP2(Cc, 5)
    COMP2(Ca, 6)

    half8 D3[8];                  // all of GEMM3's B; hides under epilogue 2
    #pragma unroll
    for (int ks = 0; ks < KS3; ++ks)
        #pragma unroll
        for (int n = 0; n < 2; ++n)
            D3[ks * 2 + n] = *reinterpret_cast<const half8*>(&B3[((ks * JT3 + n) * 64 + lane) * 8]);
    COMP2(Cb, 7)

    // epilogue 2: bias+relu -> fp16 -> A3 @16384 (disjoint from A2: no barrier before writes)
    #pragma unroll
    for (int n = 0; n < 2; ++n) {
        const int j = (wv * 2 + n) * 16 + r16;            // h2 col = GEMM3 k (0..127)
        const float bb = s_b2[j];
        const int base = 16384 + (((j >> 5) * 4 + ((j >> 3) & 3)) * G) * 8 + (j & 7);
        #pragma unroll
        for (int m = 0; m < 4; ++m)
            #pragma unroll
            for (int r = 0; r < 4; ++r) {
                const int g = m * 16 + kq * 4 + r;
                s_scr[base + g * 8] = f2h(fmaxf(acc2[m][n][r] + bb, 0.0f));
            }
    }
    __syncthreads();

    // ---- GEMM3: [64 x 128] x [128 x 22(pad32)]; wave wv owns graphs [wv*16, +16) ----
    {
        f32x4 acc3[2];
        acc3[0] = (f32x4){0.f, 0.f, 0.f, 0.f};
        acc3[1] = (f32x4){0.f, 0.f, 0.f, 0.f};
        #pragma unroll
        for (int ks = 0; ks < KS3; ++ks) {
            const half8 a = *reinterpret_cast<const half8*>(
                &s_scr[16384 + ((ks * 4 + kq) * G + (wv * 16 + r16)) * 8]);
            #pragma unroll
            for (int n = 0; n < 2; ++n)
                acc3[n] = MFMA16(a, D3[ks * 2 + n], acc3[n]);
        }
        #pragma unroll
        for (int n = 0; n < 2; ++n) {
            const int j = n * 16 + r16;
            if (j < P) {
                const float bb = s_b3[j];
                #pragma unroll
                for (int r = 0; r < 4; ++r) {
                    const int g = wv * 16 + kq * 4 + r;
                    out[(size_t)(g0 + g) * P + j] = acc3[n][r] + bb;
                }
            }
        }
    }
}

extern "C" void kernel_launch(void* const* d_in, const int* in_sizes, int n_in,
                              void* d_out, int out_size, void* d_ws, size_t ws_size,
                              hipStream_t stream) {
    const float* x     = (const float*)d_in[0];
    const int*   batch = (const int*)  d_in[1];
    const float* W1    = (const float*)d_in[2];
    const float* b1    = (const float*)d_in[3];
    const float* W2    = (const float*)d_in[4];
    const float* b2    = (const float*)d_in[5];
    const float* W3    = (const float*)d_in[6];
    const float* b3    = (const float*)d_in[7];
    float* out = (float*)d_out;

    convert_w_kernel<<<dim3((CVT_DWORDS + 255) / 256), dim3(256), 0, stream>>>(
        W1, W2, W3, (unsigned*)d_ws);
    mlp_mfma_kernel<<<dim3(NBLK), dim3(256), 0, stream>>>(
        x, batch, b1, b2, b3, (const unsigned short*)d_ws, out);
}